// Round 19
// baseline (123.422 us; speedup 1.0000x reference)
//
#include <hip/hip_runtime.h>
#include <math.h>

#define NEG_SLOPE 0.2f

typedef unsigned int u32;
typedef unsigned short u16;
typedef unsigned long long u64;

typedef __attribute__((ext_vector_type(8))) short short8;   // 8 bf16 = 4 VGPR (MFMA A/B frag)
typedef __attribute__((ext_vector_type(4))) float f32x4;    // MFMA C/D frag
typedef __attribute__((ext_vector_type(2))) float f32x2;    // packed f32 pair

__device__ __forceinline__ float bf2f(u16 h) {
  union { u32 u; float f; } c; c.u = ((u32)h) << 16; return c.f;
}
__device__ __forceinline__ u16 f2bf(float f) {
  union { float f; u32 u; } c; c.f = f;
  return (u16)((c.u + 0x7FFFu + ((c.u >> 16) & 1u)) >> 16);  // RNE, no NaNs expected
}
__device__ __forceinline__ f32x2 bf2x2(u32 pr) {
  f32x2 v;
  v.x = __uint_as_float(pr << 16);
  v.y = __uint_as_float(pr & 0xffff0000u);
  return v;
}

// ---------------------------------------------------------------- bfrag builder (device fn)
__device__ __forceinline__ void bfrag_build(const float* __restrict__ W, uint4* __restrict__ bfrag,
                                            int H, int f, int lane) {
  int p = f & 1, t = (f >> 1) & 3, cg = f >> 3;
  int colc = 16 * cg + (lane & 15);
  int k0 = 32 * t + 8 * (lane >> 4);
  u16 v[8];
  #pragma unroll
  for (int j = 0; j < 8; j++) {
    float w = W[(size_t)(k0 + j) * (H * 64) + colc];
    u32 bits = __float_as_uint(w);
    if (p == 0) v[j] = (u16)(bits >> 16);
    else        v[j] = f2bf(w - __uint_as_float(bits & 0xffff0000u));
  }
  uint4 o = { (u32)v[0] | ((u32)v[1] << 16), (u32)v[2] | ((u32)v[3] << 16),
              (u32)v[4] | ((u32)v[5] << 16), (u32)v[6] | ((u32)v[7] << 16) };
  bfrag[f * 64 + lane] = o;
}

// ---------------------------------------------------------------- fused prep: hist (0..255) + bfrag1 (256..271) + bfrag2 (272..279) + scalars (280)
__global__ __launch_bounds__(256) void k_prep(const int* __restrict__ dst, int E, int epb,
                                              u32* __restrict__ hist,
                                              const float* __restrict__ W1, uint4* __restrict__ bfrag1,
                                              const float* __restrict__ W2, uint4* __restrict__ bfrag2,
                                              const float* __restrict__ We1, const float* __restrict__ ae1,
                                              const float* __restrict__ We2, const float* __restrict__ ae2,
                                              float* __restrict__ scal) {
  int b = blockIdx.x;
  if (b < 256) {
    __shared__ u32 h[256];
    h[threadIdx.x] = 0;
    __syncthreads();
    int beg = b * epb, end = beg + epb; if (end > E) end = E;
    for (int i = beg + threadIdx.x; i < end; i += 256)
      atomicAdd(&h[(u32)dst[i] >> 8], 1u);
    __syncthreads();
    hist[threadIdx.x * 256 + b] = h[threadIdx.x];   // [bucket][block]
  } else if (b < 272) {
    int f = (b - 256) * 4 + (threadIdx.x >> 6);
    if (f < 64) bfrag_build(W1, bfrag1, 2, f, threadIdx.x & 63);
  } else if (b < 280) {
    int f = (b - 272) * 4 + (threadIdx.x >> 6);
    if (f < 32) bfrag_build(W2, bfrag2, 1, f, threadIdx.x & 63);
  } else {
    int t = threadIdx.x;
    if (t == 0) { float s = 0; for (int c = 0; c < 64; c++) s += We1[c] * ae1[c]; scal[0] = s; }
    if (t == 1) { float s = 0; for (int c = 0; c < 64; c++) s += We1[64 + c] * ae1[64 + c]; scal[1] = s; }
    if (t == 2) { float s = 0; for (int c = 0; c < 64; c++) s += We2[c] * ae2[c]; scal[2] = s; }
  }
}

// ---------------------------------------------------------------- pass B1: exclusive scan per bucket row
__global__ __launch_bounds__(256) void k_scanrow(u32* __restrict__ hist, u32* __restrict__ btot) {
  int bkt = blockIdx.x, t = threadIdx.x;
  u32 orig = hist[bkt * 256 + t];
  u32 v = orig;
  #pragma unroll
  for (int off = 1; off < 64; off <<= 1) {
    u32 u_ = __shfl_up(v, off);
    if ((t & 63) >= off) v += u_;
  }
  __shared__ u32 ws[4];
  if ((t & 63) == 63) ws[t >> 6] = v;
  __syncthreads();
  u32 add = 0; int w = t >> 6;
  if (w > 0) add += ws[0];
  if (w > 1) add += ws[1];
  if (w > 2) add += ws[2];
  u32 incl = v + add;
  hist[bkt * 256 + t] = incl - orig;   // exclusive within bucket
  if (t == 255) btot[bkt] = incl;      // bucket total
}

// shared helper: exclusive scan of btot[256] into LDS (excl + orig)
__device__ __forceinline__ void scan_btot(const u32* __restrict__ btot,
                                          u32* __restrict__ sexc, u32* __restrict__ sorig,
                                          u32* __restrict__ ws4) {
  int t = threadIdx.x;
  u32 orig = btot[t];
  u32 v = orig;
  #pragma unroll
  for (int off = 1; off < 64; off <<= 1) {
    u32 u_ = __shfl_up(v, off);
    if ((t & 63) >= off) v += u_;
  }
  if ((t & 63) == 63) ws4[t >> 6] = v;
  __syncthreads();
  u32 add = 0; int w = t >> 6;
  if (w > 0) add += ws4[0];
  if (w > 1) add += ws4[1];
  if (w > 2) add += ws4[2];
  sexc[t] = v + add - orig;
  sorig[t] = orig;
  __syncthreads();
}

// ---------------------------------------------------------------- fused: MFMA GEMM layer1 (0..nbg-1) + binscatter (nbg..nbg+255)
// stage entry u32: ln:31..24 | wq8:23..16 | src:15..0
__global__ __launch_bounds__(256) void k_gemmbin(const float* __restrict__ A,
                                                 const uint4* __restrict__ bfrag,
                                                 u16* __restrict__ xs_bf,
                                                 const float* __restrict__ att_src,
                                                 const float* __restrict__ att_dst,
                                                 float* __restrict__ a_src_out,
                                                 float* __restrict__ a_dst_out,
                                                 int nrows, int nbg,
                                                 const int* __restrict__ esrc,
                                                 const int* __restrict__ edst,
                                                 const float* __restrict__ ew,
                                                 const u32* __restrict__ hist,
                                                 const u32* __restrict__ btot,
                                                 u32* __restrict__ stage, int E, int epb) {
  if (blockIdx.x >= nbg) {
    // -------- binscatter path: recompute bstart locally from btot
    __shared__ u32 cur[256];
    __shared__ u32 sexc[256];
    __shared__ u32 sorig[256];
    __shared__ u32 ws4[4];
    int b = blockIdx.x - nbg;
    scan_btot(btot, sexc, sorig, ws4);
    cur[threadIdx.x] = sexc[threadIdx.x] + hist[threadIdx.x * 256 + b];
    __syncthreads();
    int beg = b * epb, end = beg + epb; if (end > E) end = E;
    for (int i = beg + threadIdx.x; i < end; i += 256) {
      int d = edst[i];
      u32 bkt = (u32)d >> 8;
      u32 pos = atomicAdd(&cur[bkt], 1u);
      float w = ew[i];
      u32 wq = (u32)(w * 256.0f); if (wq > 255u) wq = 255u;
      stage[pos] = (((u32)d & 255u) << 24) | (wq << 16) | (u32)esrc[i];
    }
    return;
  }
  // -------- GEMM path (H=2)
  const int H = 2;
  const int NCG = H * 4;
  int lane = threadIdx.x & 63;
  int wv = threadIdx.x >> 6;
  int lrow = lane & 15, lk = lane >> 4;
  int r0 = blockIdx.x * 64 + wv * 16;
  int arow = r0 + lrow; if (arow > nrows - 1) arow = nrows - 1;
  const float* ap = A + (size_t)arow * 128;

  f32x4 acc[NCG];
  #pragma unroll
  for (int cg = 0; cg < NCG; cg++) acc[cg] = (f32x4){0.f, 0.f, 0.f, 0.f};

  #pragma unroll
  for (int t = 0; t < 4; t++) {
    float4 av0 = *(const float4*)(ap + 32 * t + 8 * lk);
    float4 av1 = *(const float4*)(ap + 32 * t + 8 * lk + 4);
    float af[8] = {av0.x, av0.y, av0.z, av0.w, av1.x, av1.y, av1.z, av1.w};
    short8 ahi, alo;
    #pragma unroll
    for (int j = 0; j < 8; j++) {
      u32 bits = __float_as_uint(af[j]);
      ahi[j] = (short)(bits >> 16);
      alo[j] = (short)f2bf(af[j] - __uint_as_float(bits & 0xffff0000u));
    }
    #pragma unroll
    for (int cg = 0; cg < NCG; cg++) {
      union { uint4 u; short8 s; } bh, bl;
      bh.u = bfrag[((cg * 4 + t) * 2 + 0) * 64 + lane];
      bl.u = bfrag[((cg * 4 + t) * 2 + 1) * 64 + lane];
      acc[cg] = __builtin_amdgcn_mfma_f32_16x16x32_bf16(ahi, bh.s, acc[cg], 0, 0, 0);
      acc[cg] = __builtin_amdgcn_mfma_f32_16x16x32_bf16(ahi, bl.s, acc[cg], 0, 0, 0);
      acc[cg] = __builtin_amdgcn_mfma_f32_16x16x32_bf16(alo, bh.s, acc[cg], 0, 0, 0);
    }
  }

  float ps[2][4], pd[2][4];
  #pragma unroll
  for (int h = 0; h < 2; h++)
    #pragma unroll
    for (int r = 0; r < 4; r++) { ps[h][r] = 0.f; pd[h][r] = 0.f; }

  #pragma unroll
  for (int cg = 0; cg < NCG; cg++) {
    int colbase = 16 * cg + lrow;
    float asv = att_src[colbase];
    float adv = att_dst[colbase];
    const int h = cg >> 2;
    #pragma unroll
    for (int r = 0; r < 4; r++) {
      ps[h][r] += acc[cg][r] * asv;
      pd[h][r] += acc[cg][r] * adv;
      int row = r0 + 4 * lk + r;
      if (row < nrows) xs_bf[(size_t)row * (H * 64) + colbase] = f2bf(acc[cg][r]);
    }
  }
  #pragma unroll
  for (int h = 0; h < H; h++)
    #pragma unroll
    for (int r = 0; r < 4; r++)
      #pragma unroll
      for (int off = 8; off; off >>= 1) {
        ps[h][r] += __shfl_xor(ps[h][r], off);
        pd[h][r] += __shfl_xor(pd[h][r], off);
      }
  if (lrow == 0) {
    #pragma unroll
    for (int r = 0; r < 4; r++) {
      int row = r0 + 4 * lk + r;
      if (row < nrows) {
        #pragma unroll
        for (int h = 0; h < H; h++) {
          a_src_out[row * H + h] = ps[h][r];
          a_dst_out[row * H + h] = pd[h][r];
        }
      }
    }
  }
}

// ---------------------------------------------------------------- pass D: one block per bucket, single pass (u32 stage)
__global__ __launch_bounds__(256) void k_bucket(const u32* __restrict__ stage,
                                                const u32* __restrict__ btot,
                                                u32* __restrict__ col,
                                                u32* __restrict__ ninfo, int n) {
  __shared__ u32 pk[256];
  __shared__ u32 sexc[256];
  __shared__ u32 sorig[256];
  __shared__ u32 ws4[4];
  int bkt = blockIdx.x;
  pk[threadIdx.x] = 0;
  scan_btot(btot, sexc, sorig, ws4);   // includes trailing __syncthreads
  int beg = (int)sexc[bkt], end = beg + (int)sorig[bkt];
  for (int i = beg + threadIdx.x; i < end; i += 256) {
    u32 sv = stage[i];
    u32 ln = sv >> 24;
    u32 wq = (sv >> 16) & 0xFFu;
    u32 old = atomicAdd(&pk[ln], (1u << 24) | wq);
    u32 rank = old >> 24;
    if (rank < 64u)
      col[((((u32)bkt << 8) + ln) << 6) + rank] = sv & 0x00FFFFFFu;   // wq8:23..16 | src:15..0
  }
  __syncthreads();
  int v = (bkt << 8) + threadIdx.x;
  if (v < n) {
    u32 p = pk[threadIdx.x];
    u32 deg = p >> 24;
    float mean = ((float)(p & 0xFFFFFFu) * (1.0f / 256.0f)) / (float)(deg > 1 ? deg : 1);
    u32 mq = (u32)(mean * 65536.0f); if (mq > 65535u) mq = 65535u;
    u32 dc = deg > 64u ? 64u : deg;
    ninfo[v] = (dc << 16) | mq;
  }
}

// ---------------------------------------------------------------- MFMA GEMM layer 2 (A in bf16 -> 2 MFMAs per tile)
__global__ __launch_bounds__(256) void k_gemm_mfma1(const u16* __restrict__ A,
                                                    const uint4* __restrict__ bfrag,
                                                    u16* __restrict__ xs_bf,
                                                    const float* __restrict__ att_src,
                                                    const float* __restrict__ att_dst,
                                                    float* __restrict__ a_src_out,
                                                    float* __restrict__ a_dst_out,
                                                    int nrows) {
  const int NCG = 4;
  int lane = threadIdx.x & 63;
  int wv = threadIdx.x >> 6;
  int lrow = lane & 15, lk = lane >> 4;
  int r0 = blockIdx.x * 64 + wv * 16;
  int arow = r0 + lrow; if (arow > nrows - 1) arow = nrows - 1;
  const u16* ap = A + (size_t)arow * 128;

  f32x4 acc[NCG];
  #pragma unroll
  for (int cg = 0; cg < NCG; cg++) acc[cg] = (f32x4){0.f, 0.f, 0.f, 0.f};

  #pragma unroll
  for (int t = 0; t < 4; t++) {
    union { uint4 u; short8 s; } a;
    a.u = *(const uint4*)(ap + 32 * t + 8 * lk);   // 8 bf16 directly
    #pragma unroll
    for (int cg = 0; cg < NCG; cg++) {
      union { uint4 u; short8 s; } bh, bl;
      bh.u = bfrag[((cg * 4 + t) * 2 + 0) * 64 + lane];
      bl.u = bfrag[((cg * 4 + t) * 2 + 1) * 64 + lane];
      acc[cg] = __builtin_amdgcn_mfma_f32_16x16x32_bf16(a.s, bh.s, acc[cg], 0, 0, 0);
      acc[cg] = __builtin_amdgcn_mfma_f32_16x16x32_bf16(a.s, bl.s, acc[cg], 0, 0, 0);
    }
  }

  float ps[4], pd[4];
  #pragma unroll
  for (int r = 0; r < 4; r++) { ps[r] = 0.f; pd[r] = 0.f; }

  #pragma unroll
  for (int cg = 0; cg < NCG; cg++) {
    int colbase = 16 * cg + lrow;
    float asv = att_src[colbase];
    float adv = att_dst[colbase];
    #pragma unroll
    for (int r = 0; r < 4; r++) {
      ps[r] += acc[cg][r] * asv;
      pd[r] += acc[cg][r] * adv;
      int row = r0 + 4 * lk + r;
      if (row < nrows) xs_bf[(size_t)row * 64 + colbase] = f2bf(acc[cg][r]);
    }
  }
  #pragma unroll
  for (int r = 0; r < 4; r++)
    #pragma unroll
    for (int off = 8; off; off >>= 1) {
      ps[r] += __shfl_xor(ps[r], off);
      pd[r] += __shfl_xor(pd[r], off);
    }
  if (lrow == 0) {
    #pragma unroll
    for (int r = 0; r < 4; r++) {
      int row = r0 + 4 * lk + r;
      if (row < nrows) {
        a_src_out[row] = ps[r];
        a_dst_out[row] = pd[r];
      }
    }
  }
}

// ---------------------------------------------------------------- layer 1 agg: 8-lane group/node (8 nodes/wave), 16 feat/lane, ILP=2
// alpha broadcast: shuffle BOTH heads, select AFTER (round-14 lesson); hi = gl>=4
__global__ __launch_bounds__(256) void k_agg1(const u32* __restrict__ ninfo,
                                              const u32* __restrict__ col,
                                              const float2* __restrict__ a_src,
                                              const float2* __restrict__ a_dst,
                                              const float* __restrict__ scal,
                                              const u16* __restrict__ xs_bf,
                                              const float* __restrict__ b1,
                                              u16* __restrict__ h_out, int n) {
  int wid = (blockIdx.x * 256 + threadIdx.x) >> 3;
  int gl = threadIdx.x & 7;
  if (wid >= n) return;
  u32 nf = ninfo[wid];
  int deg = (int)(nf >> 16);
  float mean = (float)(nf & 0xFFFFu) * (1.0f / 65536.0f);
  float2 ad = a_dst[wid];
  float2 asv_s = a_src[wid];
  float sc0 = scal[0], sc1 = scal[1];
  bool hi = gl >= 4;                       // features 16*gl..16*gl+15; head1 at gl>=4
  float l0s = asv_s.x + ad.x + mean * sc0;
  float l1s = asv_s.y + ad.y + mean * sc1;
  l0s = l0s > 0.f ? l0s : NEG_SLOPE * l0s;
  l1s = l1s > 0.f ? l1s : NEG_SLOPE * l1s;

  const u32* cw = col + ((u32)wid << 6);
  int nch = (deg + 7) >> 3;   // <= 8

  float e0a[8], e1a[8]; int sa[8];
  #pragma unroll
  for (int c = 0; c < 8; c++) {
    float l0 = -1e30f, l1 = -1e30f; int s = 0;
    if (c < nch) {
      int p = c * 8 + gl;
      bool act = p < deg;
      u32 sw = cw[act ? p : 0];
      s = (int)(sw & 0xFFFFu);
      float w = (float)(sw >> 16) * (1.0f / 256.0f);
      float2 asv = a_src[s];
      l0 = asv.x + ad.x + w * sc0;
      l1 = asv.y + ad.y + w * sc1;
      l0 = l0 > 0.f ? l0 : NEG_SLOPE * l0;
      l1 = l1 > 0.f ? l1 : NEG_SLOPE * l1;
      if (!act) { l0 = -1e30f; l1 = -1e30f; }
    }
    sa[c] = s; e0a[c] = l0; e1a[c] = l1;
  }
  float m0 = e0a[0], m1 = e1a[0];
  #pragma unroll
  for (int c = 1; c < 8; c++) { m0 = fmaxf(m0, e0a[c]); m1 = fmaxf(m1, e1a[c]); }
  #pragma unroll
  for (int off = 4; off; off >>= 1) {
    m0 = fmaxf(m0, __shfl_xor(m0, off, 8));
    m1 = fmaxf(m1, __shfl_xor(m1, off, 8));
  }
  m0 = fmaxf(m0, l0s); m1 = fmaxf(m1, l1s);
  float d0 = 0.f, d1 = 0.f;
  #pragma unroll
  for (int c = 0; c < 8; c++) {
    float t0 = __expf(e0a[c] - m0);
    float t1 = __expf(e1a[c] - m1);
    e0a[c] = t0; e1a[c] = t1;
    d0 += t0; d1 += t1;
  }
  #pragma unroll
  for (int off = 4; off; off >>= 1) {
    d0 += __shfl_xor(d0, off, 8);
    d1 += __shfl_xor(d1, off, 8);
  }
  float es0 = __expf(l0s - m0), es1 = __expf(l1s - m1);
  float den = (hi ? d1 + es1 : d0 + es0);
  float esl = hi ? es1 : es0;

  f32x2 acc2[8];
  {
    const u16* sp = &xs_bf[(size_t)wid * 128 + 16 * gl];
    uint4 q0 = *(const uint4*)sp;
    uint4 q1 = *(const uint4*)(sp + 8);
    acc2[0] = bf2x2(q0.x) * esl; acc2[1] = bf2x2(q0.y) * esl;
    acc2[2] = bf2x2(q0.z) * esl; acc2[3] = bf2x2(q0.w) * esl;
    acc2[4] = bf2x2(q1.x) * esl; acc2[5] = bf2x2(q1.y) * esl;
    acc2[6] = bf2x2(q1.z) * esl; acc2[7] = bf2x2(q1.w) * esl;
  }
  #pragma unroll
  for (int c = 0; c < 8; c++) {
    if (c < nch) {
      int base = c * 8;
      int cnt = deg - base; if (cnt > 8) cnt = 8;
      int j = 0;
      for (; j + 2 <= cnt; j += 2) {
        int sj0 = __shfl(sa[c], j, 8);
        int sj1 = __shfl(sa[c], j + 1, 8);
        const u16* pa = &xs_bf[(size_t)sj0 * 128 + 16 * gl];
        const u16* pb = &xs_bf[(size_t)sj1 * 128 + 16 * gl];
        uint4 qa0 = *(const uint4*)pa;
        uint4 qa1 = *(const uint4*)(pa + 8);
        uint4 qb0 = *(const uint4*)pb;
        uint4 qb1 = *(const uint4*)(pb + 8);
        float a0 = __shfl(e0a[c], j, 8),     a1 = __shfl(e1a[c], j, 8);
        float b0 = __shfl(e0a[c], j + 1, 8), b1 = __shfl(e1a[c], j + 1, 8);
        float ala = hi ? a1 : a0;
        float alb = hi ? b1 : b0;
        acc2[0] += bf2x2(qa0.x) * ala; acc2[1] += bf2x2(qa0.y) * ala;
        acc2[2] += bf2x2(qa0.z) * ala; acc2[3] += bf2x2(qa0.w) * ala;
        acc2[4] += bf2x2(qa1.x) * ala; acc2[5] += bf2x2(qa1.y) * ala;
        acc2[6] += bf2x2(qa1.z) * ala; acc2[7] += bf2x2(qa1.w) * ala;
        acc2[0] += bf2x2(qb0.x) * alb; acc2[1] += bf2x2(qb0.y) * alb;
        acc2[2] += bf2x2(qb0.z) * alb; acc2[3] += bf2x2(qb0.w) * alb;
        acc2[4] += bf2x2(qb1.x) * alb; acc2[5] += bf2x2(qb1.y) * alb;
        acc2[6] += bf2x2(qb1.z) * alb; acc2[7] += bf2x2(qb1.w) * alb;
      }
      if (j < cnt) {
        int sj = __shfl(sa[c], j, 8);
        const u16* pa = &xs_bf[(size_t)sj * 128 + 16 * gl];
        uint4 q0 = *(const uint4*)pa;
        uint4 q1 = *(const uint4*)(pa + 8);
        float a0 = __shfl(e0a[c], j, 8), a1 = __shfl(e1a[c], j, 8);
        float al = hi ? a1 : a0;
        acc2[0] += bf2x2(q0.x) * al; acc2[1] += bf2x2(q0.y) * al;
        acc2[2] += bf2x2(q0.z) * al; acc2[3] += bf2x2(q0.w) * al;
        acc2[4] += bf2x2(q1.x) * al; acc2[5] += bf2x2(q1.y) * al;
        acc2[6] += bf2x2(q1.z) * al; acc2[7] += bf2x2(q1.w) * al;
      }
    }
  }
  float inv = 1.f / (den + 1e-16f);
  float o[16];
  #pragma unroll
  for (int p2 = 0; p2 < 8; p2++) {
    float2 bb = *(const float2*)&b1[16 * gl + 2 * p2];
    o[2 * p2]     = acc2[p2].x * inv + bb.x;
    o[2 * p2 + 1] = acc2[p2].y * inv + bb.y;
  }
  #pragma unroll
  for (int f = 0; f < 16; f++) o[f] = o[f] > 0.f ? o[f] : expm1f(o[f]);   // ELU
  uint4 ov0 = { (u32)f2bf(o[0])  | ((u32)f2bf(o[1])  << 16),
                (u32)f2bf(o[2])  | ((u32)f2bf(o[3])  << 16),
                (u32)f2bf(o[4])  | ((u32)f2bf(o[5])  << 16),
                (u32)f2bf(o[6])  | ((u32)f2bf(o[7])  << 16) };
  uint4 ov1 = { (u32)f2bf(o[8])  | ((u32)f2bf(o[9])  << 16),
                (u32)f2bf(o[10]) | ((u32)f2bf(o[11]) << 16),
                (u32)f2bf(o[12]) | ((u32)f2bf(o[13]) << 16),
                (u32)f2bf(o[14]) | ((u32)f2bf(o[15]) << 16) };
  u16* dst = &h_out[(size_t)wid * 128 + 16 * gl];
  *(uint4*)dst = ov0;
  *(uint4*)(dst + 8) = ov1;
}

// ---------------------------------------------------------------- layer 2 agg: 8-lane group/node, logits-first, packed-f32 accumulate
__global__ __launch_bounds__(256) void k_agg2(const u32* __restrict__ ninfo,
                                              const u32* __restrict__ col,
                                              const float* __restrict__ a_src,
                                              const float* __restrict__ a_dst,
                                              const float* __restrict__ scal,
                                              const u16* __restrict__ xs_bf,
                                              const float* __restrict__ b2,
                                              float* __restrict__ out, int n) {
  int wid = (blockIdx.x * 256 + threadIdx.x) >> 3;
  int gl = threadIdx.x & 7;
  if (wid >= n) return;
  u32 nf = ninfo[wid];
  int deg = (int)(nf >> 16);
  float mean = (float)(nf & 0xFFFFu) * (1.0f / 65536.0f);
  float adv = a_dst[wid];
  float sc = scal[2];
  float ls = a_src[wid] + adv + mean * sc;
  ls = ls > 0.f ? ls : NEG_SLOPE * ls;

  const u32* cw = col + ((u32)wid << 6);
  int nch = (deg + 7) >> 3;   // <= 8

  float ea[8]; int sa[8];
  #pragma unroll
  for (int c = 0; c < 8; c++) {
    float l = -1e30f; int s = 0;
    if (c < nch) {
      int p = c * 8 + gl;
      bool act = p < deg;
      u32 sw = cw[act ? p : 0];
      s = (int)(sw & 0xFFFFu);
      float w = (float)(sw >> 16) * (1.0f / 256.0f);
      l = a_src[s] + adv + w * sc;
      l = l > 0.f ? l : NEG_SLOPE * l;
      if (!act) l = -1e30f;
    }
    sa[c] = s; ea[c] = l;
  }
  float m = ls;
  #pragma unroll
  for (int c = 0; c < 8; c++) m = fmaxf(m, ea[c]);
  #pragma unroll
  for (int off = 4; off; off >>= 1) m = fmaxf(m, __shfl_xor(m, off, 8));
  float d = 0.f;
  #pragma unroll
  for (int c = 0; c < 8; c++) {
    float t = __expf(ea[c] - m);
    ea[c] = t; d += t;
  }
  #pragma unroll
  for (int off = 4; off; off >>= 1) d += __shfl_xor(d, off, 8);
  float es = __expf(ls - m);
  float den = d + es;

  f32x2 acc2[4];
  {
    uint4 q = *(const uint4*)&xs_bf[(size_t)wid * 64 + 8 * gl];
    acc2[0] = bf2x2(q.x) * es;
    acc2[1] = bf2x2(q.y) * es;
    acc2[2] = bf2x2(q.z) * es;
    acc2[3] = bf2x2(q.w) * es;
  }
  #pragma unroll
  for (int c = 0; c < 8; c++) {
    if (c < nch) {
      int base = c * 8;
      int cnt = deg - base; if (cnt > 8) cnt = 8;
      int j = 0;
      for (; j + 2 <= cnt; j += 2) {
        int sj0 = __shfl(sa[c], j, 8);
        int sj1 = __shfl(sa[c], j + 1, 8);
        uint4 qa = *(const uint4*)&xs_bf[(size_t)sj0 * 64 + 8 * gl];
        uint4 qb = *(const uint4*)&xs_bf[(size_t)sj1 * 64 + 8 * gl];
        float aja = __shfl(ea[c], j, 8);
        float ajb = __shfl(ea[c], j + 1, 8);
        acc2[0] += bf2x2(qa.x) * aja;
        acc2[1] += bf2x2(qa.y) * aja;
        acc2[2] += bf2x2(qa.z) * aja;
        acc2[3] += bf2x2(qa.w) * aja;
        acc2[0] += bf2x2(qb.x) * ajb;
        acc2[1] += bf2x2(qb.y) * ajb;
        acc2[2] += bf2x2(qb.z) * ajb;
        acc2[3] += bf2x2(qb.w) * ajb;
      }
      if (j < cnt) {
        int sj = __shfl(sa[c], j, 8);
        uint4 q = *(const uint4*)&xs_bf[(size_t)sj * 64 + 8 * gl];
        float aj = __shfl(ea[c], j, 8);
        acc2[0] += bf2x2(q.x) * aj;
        acc2[1] += bf2x2(q.y) * aj;
        acc2[2] += bf2x2(q.z) * aj;
        acc2[3] += bf2x2(q.w) * aj;
      }
    }
  }
  float inv = 1.f / (den + 1e-16f);
  float4 blo = *(const float4*)&b2[8 * gl];
  float4 bhi = *(const float4*)&b2[8 * gl + 4];
  float* dst = &out[(size_t)wid * 64 + 8 * gl];
  *(float4*)dst = make_float4(acc2[0].x * inv + blo.x, acc2[0].y * inv + blo.y,
                              acc2[1].x * inv + blo.z, acc2[1].y * inv + blo.w);
  *(float4*)(dst + 4) = make_float4(acc2[2].x * inv + bhi.x, acc2[2].y * inv + bhi.y,
                                    acc2[3].x * inv + bhi.z, acc2[3].y * inv + bhi.w);
}

// ================================================================ launch
extern "C" void kernel_launch(void* const* d_in, const int* in_sizes, int n_in,
                              void* d_out, int out_size, void* d_ws, size_t ws_size,
                              hipStream_t stream) {
  const float* x   = (const float*)d_in[0];
  const int*   ei  = (const int*)d_in[1];
  const float* ew  = (const float*)d_in[2];
  const float* W1  = (const float*)d_in[3];
  const float* as1 = (const float*)d_in[4];
  const float* ad1 = (const float*)d_in[5];
  const float* We1 = (const float*)d_in[6];
  const float* ae1 = (const float*)d_in[7];
  const float* b1  = (const float*)d_in[8];
  const float* W2  = (const float*)d_in[9];
  const float* as2 = (const float*)d_in[10];
  const float* ad2 = (const float*)d_in[11];
  const float* We2 = (const float*)d_in[12];
  const float* ae2 = (const float*)d_in[13];
  const float* b2  = (const float*)d_in[14];

  const int n = in_sizes[0] / 128;
  const int E = in_sizes[1] / 2;
  const int epb = (E + 255) / 256;
  const int nbk = (n + 255) >> 8;       // used buckets
  const int nbg = (n + 63) / 64;        // gemm layer-1 blocks

  char* wsb = (char*)d_ws;
  size_t off = 0;
  auto alloc = [&](size_t bytes) -> void* {
    void* p = wsb + off; off += (bytes + 255) & ~(size_t)255; return p;
  };
  u32*   hist    = (u32*)  alloc((size_t)256 * 256 * 4);
  u32*   btot    = (u32*)  alloc((size_t)256 * 4);
  u32*   stage   = (u32*)  alloc((size_t)E * 4);         // ln:8|wq8:8|src:16
  u32*   col     = (u32*)  alloc((size_t)n * 64 * 4);    // 64 dense slots/node: wq8<<16|src
  u32*   ninfo   = (u32*)  alloc((size_t)n * 4);         // deg<<16 | mean_fix16
  uint4* bfrag1  = (uint4*)alloc((size_t)64 * 64 * 16);
  uint4* bfrag2  = (uint4*)alloc((size_t)32 * 64 * 16);
  u16*   xs_bf   = (u16*)  alloc((size_t)n * 128 * 2);   // layer1; reused layer2 (n*64)
  u16*   h1      = (u16*)  alloc((size_t)n * 128 * 2);   // bf16 hidden
  float* a_src1v = (float*)alloc((size_t)n * 2 * 4);
  float* a_dst1v = (float*)alloc((size_t)n * 2 * 4);
  float* a_src2v = (float*)alloc((size_t)n * 4);
  float* a_dst2v = (float*)alloc((size_t)n * 4);
  float* scal    = (float*)alloc(64);
  if (off > ws_size) return;

  dim3 B(256);
  k_prep<<<dim3(281), B, 0, stream>>>(ei + E, E, epb, hist, W1, bfrag1, W2, bfrag2,
                                      We1, ae1, We2, ae2, scal);
  k_scanrow<<<dim3(256), B, 0, stream>>>(hist, btot);
  // fused: gemm layer-1 || binscatter (bstart recomputed locally from btot)
  k_gemmbin<<<dim3(nbg + 256), B, 0, stream>>>(x, bfrag1, xs_bf, as1, ad1,
                                               a_src1v, a_dst1v, n, nbg,
                                               ei, ei + E, ew, hist, btot, stage, E, epb);
  k_bucket<<<dim3(nbk), B, 0, stream>>>(stage, btot, col, ninfo, n);
  k_agg1<<<dim3((n + 31) / 32), B, 0, stream>>>(ninfo, col,
                                                (const float2*)a_src1v,
                                                (const float2*)a_dst1v,
                                                scal, xs_bf, b1, h1, n);
  k_gemm_mfma1<<<dim3((n + 63) / 64), B, 0, stream>>>(h1, bfrag2, xs_bf, as2, ad2,
                                                      a_src2v, a_dst2v, n);
  k_agg2<<<dim3((n + 31) / 32), B, 0, stream>>>(ninfo, col, a_src2v, a_dst2v,
                                                scal, xs_bf, b2, (float*)d_out, n);
}

// Round 20
// 118.765 us; speedup vs baseline: 1.0392x; 1.0392x over previous
//
#include <hip/hip_runtime.h>
#include <math.h>

#define NEG_SLOPE 0.2f

typedef unsigned int u32;
typedef unsigned short u16;
typedef unsigned long long u64;

typedef __attribute__((ext_vector_type(8))) short short8;   // 8 bf16 = 4 VGPR (MFMA A/B frag)
typedef __attribute__((ext_vector_type(4))) float f32x4;    // MFMA C/D frag
typedef __attribute__((ext_vector_type(2))) float f32x2;    // packed f32 pair

__device__ __forceinline__ float bf2f(u16 h) {
  union { u32 u; float f; } c; c.u = ((u32)h) << 16; return c.f;
}
__device__ __forceinline__ u16 f2bf(float f) {
  union { float f; u32 u; } c; c.f = f;
  return (u16)((c.u + 0x7FFFu + ((c.u >> 16) & 1u)) >> 16);  // RNE, no NaNs expected
}
__device__ __forceinline__ f32x2 bf2x2(u32 pr) {
  f32x2 v;
  v.x = __uint_as_float(pr << 16);
  v.y = __uint_as_float(pr & 0xffff0000u);
  return v;
}

// ---------------------------------------------------------------- bfrag builder (device fn)
__device__ __forceinline__ void bfrag_build(const float* __restrict__ W, uint4* __restrict__ bfrag,
                                            int H, int f, int lane) {
  int p = f & 1, t = (f >> 1) & 3, cg = f >> 3;
  int colc = 16 * cg + (lane & 15);
  int k0 = 32 * t + 8 * (lane >> 4);
  u16 v[8];
  #pragma unroll
  for (int j = 0; j < 8; j++) {
    float w = W[(size_t)(k0 + j) * (H * 64) + colc];
    u32 bits = __float_as_uint(w);
    if (p == 0) v[j] = (u16)(bits >> 16);
    else        v[j] = f2bf(w - __uint_as_float(bits & 0xffff0000u));
  }
  uint4 o = { (u32)v[0] | ((u32)v[1] << 16), (u32)v[2] | ((u32)v[3] << 16),
              (u32)v[4] | ((u32)v[5] << 16), (u32)v[6] | ((u32)v[7] << 16) };
  bfrag[f * 64 + lane] = o;
}

// ---------------------------------------------------------------- fused prep: hist (0..255) + bfrag1 (256..271) + bfrag2 (272..279) + scalars (280)
__global__ __launch_bounds__(256) void k_prep(const int* __restrict__ dst, int E, int epb,
                                              u32* __restrict__ hist,
                                              const float* __restrict__ W1, uint4* __restrict__ bfrag1,
                                              const float* __restrict__ W2, uint4* __restrict__ bfrag2,
                                              const float* __restrict__ We1, const float* __restrict__ ae1,
                                              const float* __restrict__ We2, const float* __restrict__ ae2,
                                              float* __restrict__ scal) {
  int b = blockIdx.x;
  if (b < 256) {
    __shared__ u32 h[256];
    h[threadIdx.x] = 0;
    __syncthreads();
    int beg = b * epb, end = beg + epb; if (end > E) end = E;
    for (int i = beg + threadIdx.x; i < end; i += 256)
      atomicAdd(&h[(u32)dst[i] >> 8], 1u);
    __syncthreads();
    hist[threadIdx.x * 256 + b] = h[threadIdx.x];   // [bucket][block]
  } else if (b < 272) {
    int f = (b - 256) * 4 + (threadIdx.x >> 6);
    if (f < 64) bfrag_build(W1, bfrag1, 2, f, threadIdx.x & 63);
  } else if (b < 280) {
    int f = (b - 272) * 4 + (threadIdx.x >> 6);
    if (f < 32) bfrag_build(W2, bfrag2, 1, f, threadIdx.x & 63);
  } else {
    int t = threadIdx.x;
    if (t == 0) { float s = 0; for (int c = 0; c < 64; c++) s += We1[c] * ae1[c]; scal[0] = s; }
    if (t == 1) { float s = 0; for (int c = 0; c < 64; c++) s += We1[64 + c] * ae1[64 + c]; scal[1] = s; }
    if (t == 2) { float s = 0; for (int c = 0; c < 64; c++) s += We2[c] * ae2[c]; scal[2] = s; }
  }
}

// ---------------------------------------------------------------- pass B1: exclusive scan per bucket row
__global__ __launch_bounds__(256) void k_scanrow(u32* __restrict__ hist, u32* __restrict__ btot) {
  int bkt = blockIdx.x, t = threadIdx.x;
  u32 orig = hist[bkt * 256 + t];
  u32 v = orig;
  #pragma unroll
  for (int off = 1; off < 64; off <<= 1) {
    u32 u_ = __shfl_up(v, off);
    if ((t & 63) >= off) v += u_;
  }
  __shared__ u32 ws[4];
  if ((t & 63) == 63) ws[t >> 6] = v;
  __syncthreads();
  u32 add = 0; int w = t >> 6;
  if (w > 0) add += ws[0];
  if (w > 1) add += ws[1];
  if (w > 2) add += ws[2];
  u32 incl = v + add;
  hist[bkt * 256 + t] = incl - orig;   // exclusive within bucket
  if (t == 255) btot[bkt] = incl;      // bucket total
}

// shared helper: exclusive scan of btot[256] into LDS (excl + orig)
__device__ __forceinline__ void scan_btot(const u32* __restrict__ btot,
                                          u32* __restrict__ sexc, u32* __restrict__ sorig,
                                          u32* __restrict__ ws4) {
  int t = threadIdx.x;
  u32 orig = btot[t];
  u32 v = orig;
  #pragma unroll
  for (int off = 1; off < 64; off <<= 1) {
    u32 u_ = __shfl_up(v, off);
    if ((t & 63) >= off) v += u_;
  }
  if ((t & 63) == 63) ws4[t >> 6] = v;
  __syncthreads();
  u32 add = 0; int w = t >> 6;
  if (w > 0) add += ws4[0];
  if (w > 1) add += ws4[1];
  if (w > 2) add += ws4[2];
  sexc[t] = v + add - orig;
  sorig[t] = orig;
  __syncthreads();
}

// ---------------------------------------------------------------- fused: MFMA GEMM layer1 (0..nbg-1) + binscatter (nbg..nbg+255)
// stage entry u32: ln:31..24 | wq8:23..16 | src:15..0
__global__ __launch_bounds__(256) void k_gemmbin(const float* __restrict__ A,
                                                 const uint4* __restrict__ bfrag,
                                                 u16* __restrict__ xs_bf,
                                                 const float* __restrict__ att_src,
                                                 const float* __restrict__ att_dst,
                                                 float* __restrict__ a_src_out,
                                                 float* __restrict__ a_dst_out,
                                                 int nrows, int nbg,
                                                 const int* __restrict__ esrc,
                                                 const int* __restrict__ edst,
                                                 const float* __restrict__ ew,
                                                 const u32* __restrict__ hist,
                                                 const u32* __restrict__ btot,
                                                 u32* __restrict__ stage, int E, int epb) {
  if (blockIdx.x >= nbg) {
    // -------- binscatter path: recompute bstart locally from btot
    __shared__ u32 cur[256];
    __shared__ u32 sexc[256];
    __shared__ u32 sorig[256];
    __shared__ u32 ws4[4];
    int b = blockIdx.x - nbg;
    scan_btot(btot, sexc, sorig, ws4);
    cur[threadIdx.x] = sexc[threadIdx.x] + hist[threadIdx.x * 256 + b];
    __syncthreads();
    int beg = b * epb, end = beg + epb; if (end > E) end = E;
    for (int i = beg + threadIdx.x; i < end; i += 256) {
      int d = edst[i];
      u32 bkt = (u32)d >> 8;
      u32 pos = atomicAdd(&cur[bkt], 1u);
      float w = ew[i];
      u32 wq = (u32)(w * 256.0f); if (wq > 255u) wq = 255u;
      stage[pos] = (((u32)d & 255u) << 24) | (wq << 16) | (u32)esrc[i];
    }
    return;
  }
  // -------- GEMM path (H=2)
  const int H = 2;
  const int NCG = H * 4;
  int lane = threadIdx.x & 63;
  int wv = threadIdx.x >> 6;
  int lrow = lane & 15, lk = lane >> 4;
  int r0 = blockIdx.x * 64 + wv * 16;
  int arow = r0 + lrow; if (arow > nrows - 1) arow = nrows - 1;
  const float* ap = A + (size_t)arow * 128;

  f32x4 acc[NCG];
  #pragma unroll
  for (int cg = 0; cg < NCG; cg++) acc[cg] = (f32x4){0.f, 0.f, 0.f, 0.f};

  #pragma unroll
  for (int t = 0; t < 4; t++) {
    float4 av0 = *(const float4*)(ap + 32 * t + 8 * lk);
    float4 av1 = *(const float4*)(ap + 32 * t + 8 * lk + 4);
    float af[8] = {av0.x, av0.y, av0.z, av0.w, av1.x, av1.y, av1.z, av1.w};
    short8 ahi, alo;
    #pragma unroll
    for (int j = 0; j < 8; j++) {
      u32 bits = __float_as_uint(af[j]);
      ahi[j] = (short)(bits >> 16);
      alo[j] = (short)f2bf(af[j] - __uint_as_float(bits & 0xffff0000u));
    }
    #pragma unroll
    for (int cg = 0; cg < NCG; cg++) {
      union { uint4 u; short8 s; } bh, bl;
      bh.u = bfrag[((cg * 4 + t) * 2 + 0) * 64 + lane];
      bl.u = bfrag[((cg * 4 + t) * 2 + 1) * 64 + lane];
      acc[cg] = __builtin_amdgcn_mfma_f32_16x16x32_bf16(ahi, bh.s, acc[cg], 0, 0, 0);
      acc[cg] = __builtin_amdgcn_mfma_f32_16x16x32_bf16(ahi, bl.s, acc[cg], 0, 0, 0);
      acc[cg] = __builtin_amdgcn_mfma_f32_16x16x32_bf16(alo, bh.s, acc[cg], 0, 0, 0);
    }
  }

  float ps[2][4], pd[2][4];
  #pragma unroll
  for (int h = 0; h < 2; h++)
    #pragma unroll
    for (int r = 0; r < 4; r++) { ps[h][r] = 0.f; pd[h][r] = 0.f; }

  #pragma unroll
  for (int cg = 0; cg < NCG; cg++) {
    int colbase = 16 * cg + lrow;
    float asv = att_src[colbase];
    float adv = att_dst[colbase];
    const int h = cg >> 2;
    #pragma unroll
    for (int r = 0; r < 4; r++) {
      ps[h][r] += acc[cg][r] * asv;
      pd[h][r] += acc[cg][r] * adv;
      int row = r0 + 4 * lk + r;
      if (row < nrows) xs_bf[(size_t)row * (H * 64) + colbase] = f2bf(acc[cg][r]);
    }
  }
  #pragma unroll
  for (int h = 0; h < H; h++)
    #pragma unroll
    for (int r = 0; r < 4; r++)
      #pragma unroll
      for (int off = 8; off; off >>= 1) {
        ps[h][r] += __shfl_xor(ps[h][r], off);
        pd[h][r] += __shfl_xor(pd[h][r], off);
      }
  if (lrow == 0) {
    #pragma unroll
    for (int r = 0; r < 4; r++) {
      int row = r0 + 4 * lk + r;
      if (row < nrows) {
        #pragma unroll
        for (int h = 0; h < H; h++) {
          a_src_out[row * H + h] = ps[h][r];
          a_dst_out[row * H + h] = pd[h][r];
        }
      }
    }
  }
}

// ---------------------------------------------------------------- pass D: one block per bucket, single pass (u32 stage)
__global__ __launch_bounds__(256) void k_bucket(const u32* __restrict__ stage,
                                                const u32* __restrict__ btot,
                                                u32* __restrict__ col,
                                                u32* __restrict__ ninfo, int n) {
  __shared__ u32 pk[256];
  __shared__ u32 sexc[256];
  __shared__ u32 sorig[256];
  __shared__ u32 ws4[4];
  int bkt = blockIdx.x;
  pk[threadIdx.x] = 0;
  scan_btot(btot, sexc, sorig, ws4);   // includes trailing __syncthreads
  int beg = (int)sexc[bkt], end = beg + (int)sorig[bkt];
  for (int i = beg + threadIdx.x; i < end; i += 256) {
    u32 sv = stage[i];
    u32 ln = sv >> 24;
    u32 wq = (sv >> 16) & 0xFFu;
    u32 old = atomicAdd(&pk[ln], (1u << 24) | wq);
    u32 rank = old >> 24;
    if (rank < 64u)
      col[((((u32)bkt << 8) + ln) << 6) + rank] = sv & 0x00FFFFFFu;   // wq8:23..16 | src:15..0
  }
  __syncthreads();
  int v = (bkt << 8) + threadIdx.x;
  if (v < n) {
    u32 p = pk[threadIdx.x];
    u32 deg = p >> 24;
    float mean = ((float)(p & 0xFFFFFFu) * (1.0f / 256.0f)) / (float)(deg > 1 ? deg : 1);
    u32 mq = (u32)(mean * 65536.0f); if (mq > 65535u) mq = 65535u;
    u32 dc = deg > 64u ? 64u : deg;
    ninfo[v] = (dc << 16) | mq;
  }
}

// ---------------------------------------------------------------- MFMA GEMM layer 2 (A in bf16 -> 2 MFMAs per tile)
__global__ __launch_bounds__(256) void k_gemm_mfma1(const u16* __restrict__ A,
                                                    const uint4* __restrict__ bfrag,
                                                    u16* __restrict__ xs_bf,
                                                    const float* __restrict__ att_src,
                                                    const float* __restrict__ att_dst,
                                                    float* __restrict__ a_src_out,
                                                    float* __restrict__ a_dst_out,
                                                    int nrows) {
  const int NCG = 4;
  int lane = threadIdx.x & 63;
  int wv = threadIdx.x >> 6;
  int lrow = lane & 15, lk = lane >> 4;
  int r0 = blockIdx.x * 64 + wv * 16;
  int arow = r0 + lrow; if (arow > nrows - 1) arow = nrows - 1;
  const u16* ap = A + (size_t)arow * 128;

  f32x4 acc[NCG];
  #pragma unroll
  for (int cg = 0; cg < NCG; cg++) acc[cg] = (f32x4){0.f, 0.f, 0.f, 0.f};

  #pragma unroll
  for (int t = 0; t < 4; t++) {
    union { uint4 u; short8 s; } a;
    a.u = *(const uint4*)(ap + 32 * t + 8 * lk);   // 8 bf16 directly
    #pragma unroll
    for (int cg = 0; cg < NCG; cg++) {
      union { uint4 u; short8 s; } bh, bl;
      bh.u = bfrag[((cg * 4 + t) * 2 + 0) * 64 + lane];
      bl.u = bfrag[((cg * 4 + t) * 2 + 1) * 64 + lane];
      acc[cg] = __builtin_amdgcn_mfma_f32_16x16x32_bf16(a.s, bh.s, acc[cg], 0, 0, 0);
      acc[cg] = __builtin_amdgcn_mfma_f32_16x16x32_bf16(a.s, bl.s, acc[cg], 0, 0, 0);
    }
  }

  float ps[4], pd[4];
  #pragma unroll
  for (int r = 0; r < 4; r++) { ps[r] = 0.f; pd[r] = 0.f; }

  #pragma unroll
  for (int cg = 0; cg < NCG; cg++) {
    int colbase = 16 * cg + lrow;
    float asv = att_src[colbase];
    float adv = att_dst[colbase];
    #pragma unroll
    for (int r = 0; r < 4; r++) {
      ps[r] += acc[cg][r] * asv;
      pd[r] += acc[cg][r] * adv;
      int row = r0 + 4 * lk + r;
      if (row < nrows) xs_bf[(size_t)row * 64 + colbase] = f2bf(acc[cg][r]);
    }
  }
  #pragma unroll
  for (int r = 0; r < 4; r++)
    #pragma unroll
    for (int off = 8; off; off >>= 1) {
      ps[r] += __shfl_xor(ps[r], off);
      pd[r] += __shfl_xor(pd[r], off);
    }
  if (lrow == 0) {
    #pragma unroll
    for (int r = 0; r < 4; r++) {
      int row = r0 + 4 * lk + r;
      if (row < nrows) {
        a_src_out[row] = ps[r];
        a_dst_out[row] = pd[r];
      }
    }
  }
}

// ---------------------------------------------------------------- layer 1 agg: 16-lane group/node, logits-first, bf16 h-output
// alpha broadcast: shuffle BOTH heads, select AFTER (round-14 lesson)
__global__ __launch_bounds__(256) void k_agg1(const u32* __restrict__ ninfo,
                                              const u32* __restrict__ col,
                                              const float2* __restrict__ a_src,
                                              const float2* __restrict__ a_dst,
                                              const float* __restrict__ scal,
                                              const u16* __restrict__ xs_bf,
                                              const float* __restrict__ b1,
                                              u16* __restrict__ h_out, int n) {
  int wid = (blockIdx.x * 256 + threadIdx.x) >> 4;
  int gl = threadIdx.x & 15;
  if (wid >= n) return;
  u32 nf = ninfo[wid];
  int deg = (int)(nf >> 16);
  float mean = (float)(nf & 0xFFFFu) * (1.0f / 65536.0f);
  float2 ad = a_dst[wid];
  float2 asv_s = a_src[wid];
  float sc0 = scal[0], sc1 = scal[1];
  bool hi = gl >= 8;
  float l0s = asv_s.x + ad.x + mean * sc0;
  float l1s = asv_s.y + ad.y + mean * sc1;
  l0s = l0s > 0.f ? l0s : NEG_SLOPE * l0s;
  l1s = l1s > 0.f ? l1s : NEG_SLOPE * l1s;

  const u32* cw = col + ((u32)wid << 6);
  int nch = (deg + 15) >> 4;   // <= 4

  float e0a[4], e1a[4]; int sa[4];
  #pragma unroll
  for (int c = 0; c < 4; c++) {
    float l0 = -1e30f, l1 = -1e30f; int s = 0;
    if (c < nch) {
      int p = c * 16 + gl;
      bool act = p < deg;
      u32 sw = cw[act ? p : 0];
      s = (int)(sw & 0xFFFFu);
      float w = (float)(sw >> 16) * (1.0f / 256.0f);
      float2 asv = a_src[s];
      l0 = asv.x + ad.x + w * sc0;
      l1 = asv.y + ad.y + w * sc1;
      l0 = l0 > 0.f ? l0 : NEG_SLOPE * l0;
      l1 = l1 > 0.f ? l1 : NEG_SLOPE * l1;
      if (!act) { l0 = -1e30f; l1 = -1e30f; }
    }
    sa[c] = s; e0a[c] = l0; e1a[c] = l1;
  }
  float m0 = fmaxf(fmaxf(e0a[0], e0a[1]), fmaxf(e0a[2], e0a[3]));
  float m1 = fmaxf(fmaxf(e1a[0], e1a[1]), fmaxf(e1a[2], e1a[3]));
  #pragma unroll
  for (int off = 8; off; off >>= 1) {
    m0 = fmaxf(m0, __shfl_xor(m0, off, 16));
    m1 = fmaxf(m1, __shfl_xor(m1, off, 16));
  }
  m0 = fmaxf(m0, l0s); m1 = fmaxf(m1, l1s);
  float d0 = 0.f, d1 = 0.f;
  #pragma unroll
  for (int c = 0; c < 4; c++) {
    float t0 = __expf(e0a[c] - m0);
    float t1 = __expf(e1a[c] - m1);
    e0a[c] = t0; e1a[c] = t1;
    d0 += t0; d1 += t1;
  }
  #pragma unroll
  for (int off = 8; off; off >>= 1) {
    d0 += __shfl_xor(d0, off, 16);
    d1 += __shfl_xor(d1, off, 16);
  }
  float es0 = __expf(l0s - m0), es1 = __expf(l1s - m1);
  float den = (hi ? d1 + es1 : d0 + es0);
  float esl = hi ? es1 : es0;

  f32x2 acc2[4];
  {
    uint4 q = *(const uint4*)&xs_bf[(size_t)wid * 128 + 8 * gl];
    acc2[0] = bf2x2(q.x) * esl;
    acc2[1] = bf2x2(q.y) * esl;
    acc2[2] = bf2x2(q.z) * esl;
    acc2[3] = bf2x2(q.w) * esl;
  }
  #pragma unroll
  for (int c = 0; c < 4; c++) {
    if (c < nch) {
      int base = c * 16;
      int cnt = deg - base; if (cnt > 16) cnt = 16;
      int j = 0;
      for (; j + 2 <= cnt; j += 2) {
        int sj0 = __shfl(sa[c], j, 16);
        int sj1 = __shfl(sa[c], j + 1, 16);
        uint4 qa = *(const uint4*)&xs_bf[(size_t)sj0 * 128 + 8 * gl];
        uint4 qb = *(const uint4*)&xs_bf[(size_t)sj1 * 128 + 8 * gl];
        float a0 = __shfl(e0a[c], j, 16),     a1 = __shfl(e1a[c], j, 16);
        float b0 = __shfl(e0a[c], j + 1, 16), b1 = __shfl(e1a[c], j + 1, 16);
        float ala = hi ? a1 : a0;
        float alb = hi ? b1 : b0;
        acc2[0] += bf2x2(qa.x) * ala;
        acc2[1] += bf2x2(qa.y) * ala;
        acc2[2] += bf2x2(qa.z) * ala;
        acc2[3] += bf2x2(qa.w) * ala;
        acc2[0] += bf2x2(qb.x) * alb;
        acc2[1] += bf2x2(qb.y) * alb;
        acc2[2] += bf2x2(qb.z) * alb;
        acc2[3] += bf2x2(qb.w) * alb;
      }
      if (j < cnt) {
        int sj = __shfl(sa[c], j, 16);
        uint4 q = *(const uint4*)&xs_bf[(size_t)sj * 128 + 8 * gl];
        float a0 = __shfl(e0a[c], j, 16), a1 = __shfl(e1a[c], j, 16);
        float al = hi ? a1 : a0;
        acc2[0] += bf2x2(q.x) * al;
        acc2[1] += bf2x2(q.y) * al;
        acc2[2] += bf2x2(q.z) * al;
        acc2[3] += bf2x2(q.w) * al;
      }
    }
  }
  float inv = 1.f / (den + 1e-16f);
  float4 blo = *(const float4*)&b1[8 * gl];
  float4 bhi = *(const float4*)&b1[8 * gl + 4];
  float o[8];
  o[0] = acc2[0].x * inv + blo.x; o[1] = acc2[0].y * inv + blo.y;
  o[2] = acc2[1].x * inv + blo.z; o[3] = acc2[1].y * inv + blo.w;
  o[4] = acc2[2].x * inv + bhi.x; o[5] = acc2[2].y * inv + bhi.y;
  o[6] = acc2[3].x * inv + bhi.z; o[7] = acc2[3].y * inv + bhi.w;
  #pragma unroll
  for (int f = 0; f < 8; f++) o[f] = o[f] > 0.f ? o[f] : expm1f(o[f]);   // ELU
  uint4 ov = { (u32)f2bf(o[0]) | ((u32)f2bf(o[1]) << 16),
               (u32)f2bf(o[2]) | ((u32)f2bf(o[3]) << 16),
               (u32)f2bf(o[4]) | ((u32)f2bf(o[5]) << 16),
               (u32)f2bf(o[6]) | ((u32)f2bf(o[7]) << 16) };
  *(uint4*)&h_out[(size_t)wid * 128 + 8 * gl] = ov;
}

// ---------------------------------------------------------------- layer 2 agg: 8-lane group/node, logits-first, packed-f32 accumulate
__global__ __launch_bounds__(256) void k_agg2(const u32* __restrict__ ninfo,
                                              const u32* __restrict__ col,
                                              const float* __restrict__ a_src,
                                              const float* __restrict__ a_dst,
                                              const float* __restrict__ scal,
                                              const u16* __restrict__ xs_bf,
                                              const float* __restrict__ b2,
                                              float* __restrict__ out, int n) {
  int wid = (blockIdx.x * 256 + threadIdx.x) >> 3;
  int gl = threadIdx.x & 7;
  if (wid >= n) return;
  u32 nf = ninfo[wid];
  int deg = (int)(nf >> 16);
  float mean = (float)(nf & 0xFFFFu) * (1.0f / 65536.0f);
  float adv = a_dst[wid];
  float sc = scal[2];
  float ls = a_src[wid] + adv + mean * sc;
  ls = ls > 0.f ? ls : NEG_SLOPE * ls;

  const u32* cw = col + ((u32)wid << 6);
  int nch = (deg + 7) >> 3;   // <= 8

  float ea[8]; int sa[8];
  #pragma unroll
  for (int c = 0; c < 8; c++) {
    float l = -1e30f; int s = 0;
    if (c < nch) {
      int p = c * 8 + gl;
      bool act = p < deg;
      u32 sw = cw[act ? p : 0];
      s = (int)(sw & 0xFFFFu);
      float w = (float)(sw >> 16) * (1.0f / 256.0f);
      l = a_src[s] + adv + w * sc;
      l = l > 0.f ? l : NEG_SLOPE * l;
      if (!act) l = -1e30f;
    }
    sa[c] = s; ea[c] = l;
  }
  float m = ls;
  #pragma unroll
  for (int c = 0; c < 8; c++) m = fmaxf(m, ea[c]);
  #pragma unroll
  for (int off = 4; off; off >>= 1) m = fmaxf(m, __shfl_xor(m, off, 8));
  float d = 0.f;
  #pragma unroll
  for (int c = 0; c < 8; c++) {
    float t = __expf(ea[c] - m);
    ea[c] = t; d += t;
  }
  #pragma unroll
  for (int off = 4; off; off >>= 1) d += __shfl_xor(d, off, 8);
  float es = __expf(ls - m);
  float den = d + es;

  f32x2 acc2[4];
  {
    uint4 q = *(const uint4*)&xs_bf[(size_t)wid * 64 + 8 * gl];
    acc2[0] = bf2x2(q.x) * es;
    acc2[1] = bf2x2(q.y) * es;
    acc2[2] = bf2x2(q.z) * es;
    acc2[3] = bf2x2(q.w) * es;
  }
  #pragma unroll
  for (int c = 0; c < 8; c++) {
    if (c < nch) {
      int base = c * 8;
      int cnt = deg - base; if (cnt > 8) cnt = 8;
      int j = 0;
      for (; j + 2 <= cnt; j += 2) {
        int sj0 = __shfl(sa[c], j, 8);
        int sj1 = __shfl(sa[c], j + 1, 8);
        uint4 qa = *(const uint4*)&xs_bf[(size_t)sj0 * 64 + 8 * gl];
        uint4 qb = *(const uint4*)&xs_bf[(size_t)sj1 * 64 + 8 * gl];
        float aja = __shfl(ea[c], j, 8);
        float ajb = __shfl(ea[c], j + 1, 8);
        acc2[0] += bf2x2(qa.x) * aja;
        acc2[1] += bf2x2(qa.y) * aja;
        acc2[2] += bf2x2(qa.z) * aja;
        acc2[3] += bf2x2(qa.w) * aja;
        acc2[0] += bf2x2(qb.x) * ajb;
        acc2[1] += bf2x2(qb.y) * ajb;
        acc2[2] += bf2x2(qb.z) * ajb;
        acc2[3] += bf2x2(qb.w) * ajb;
      }
      if (j < cnt) {
        int sj = __shfl(sa[c], j, 8);
        uint4 q = *(const uint4*)&xs_bf[(size_t)sj * 64 + 8 * gl];
        float aj = __shfl(ea[c], j, 8);
        acc2[0] += bf2x2(q.x) * aj;
        acc2[1] += bf2x2(q.y) * aj;
        acc2[2] += bf2x2(q.z) * aj;
        acc2[3] += bf2x2(q.w) * aj;
      }
    }
  }
  float inv = 1.f / (den + 1e-16f);
  float4 blo = *(const float4*)&b2[8 * gl];
  float4 bhi = *(const float4*)&b2[8 * gl + 4];
  float* dst = &out[(size_t)wid * 64 + 8 * gl];
  *(float4*)dst = make_float4(acc2[0].x * inv + blo.x, acc2[0].y * inv + blo.y,
                              acc2[1].x * inv + blo.z, acc2[1].y * inv + blo.w);
  *(float4*)(dst + 4) = make_float4(acc2[2].x * inv + bhi.x, acc2[2].y * inv + bhi.y,
                                    acc2[3].x * inv + bhi.z, acc2[3].y * inv + bhi.w);
}

// ================================================================ launch
extern "C" void kernel_launch(void* const* d_in, const int* in_sizes, int n_in,
                              void* d_out, int out_size, void* d_ws, size_t ws_size,
                              hipStream_t stream) {
  const float* x   = (const float*)d_in[0];
  const int*   ei  = (const int*)d_in[1];
  const float* ew  = (const float*)d_in[2];
  const float* W1  = (const float*)d_in[3];
  const float* as1 = (const float*)d_in[4];
  const float* ad1 = (const float*)d_in[5];
  const float* We1 = (const float*)d_in[6];
  const float* ae1 = (const float*)d_in[7];
  const float* b1  = (const float*)d_in[8];
  const float* W2  = (const float*)d_in[9];
  const float* as2 = (const float*)d_in[10];
  const float* ad2 = (const float*)d_in[11];
  const float* We2 = (const float*)d_in[12];
  const float* ae2 = (const float*)d_in[13];
  const float* b2  = (const float*)d_in[14];

  const int n = in_sizes[0] / 128;
  const int E = in_sizes[1] / 2;
  const int epb = (E + 255) / 256;
  const int nbk = (n + 255) >> 8;       // used buckets
  const int nbg = (n + 63) / 64;        // gemm layer-1 blocks

  char* wsb = (char*)d_ws;
  size_t off = 0;
  auto alloc = [&](size_t bytes) -> void* {
    void* p = wsb + off; off += (bytes + 255) & ~(size_t)255; return p;
  };
  u32*   hist    = (u32*)  alloc((size_t)256 * 256 * 4);
  u32*   btot    = (u32*)  alloc((size_t)256 * 4);
  u32*   stage   = (u32*)  alloc((size_t)E * 4);         // ln:8|wq8:8|src:16
  u32*   col     = (u32*)  alloc((size_t)n * 64 * 4);    // 64 dense slots/node: wq8<<16|src
  u32*   ninfo   = (u32*)  alloc((size_t)n * 4);         // deg<<16 | mean_fix16
  uint4* bfrag1  = (uint4*)alloc((size_t)64 * 64 * 16);
  uint4* bfrag2  = (uint4*)alloc((size_t)32 * 64 * 16);
  u16*   xs_bf   = (u16*)  alloc((size_t)n * 128 * 2);   // layer1; reused layer2 (n*64)
  u16*   h1      = (u16*)  alloc((size_t)n * 128 * 2);   // bf16 hidden
  float* a_src1v = (float*)alloc((size_t)n * 2 * 4);
  float* a_dst1v = (float*)alloc((size_t)n * 2 * 4);
  float* a_src2v = (float*)alloc((size_t)n * 4);
  float* a_dst2v = (float*)alloc((size_t)n * 4);
  float* scal    = (float*)alloc(64);
  if (off > ws_size) return;

  dim3 B(256);
  k_prep<<<dim3(281), B, 0, stream>>>(ei + E, E, epb, hist, W1, bfrag1, W2, bfrag2,
                                      We1, ae1, We2, ae2, scal);
  k_scanrow<<<dim3(256), B, 0, stream>>>(hist, btot);
  // fused: gemm layer-1 || binscatter (bstart recomputed locally from btot)
  k_gemmbin<<<dim3(nbg + 256), B, 0, stream>>>(x, bfrag1, xs_bf, as1, ad1,
                                               a_src1v, a_dst1v, n, nbg,
                                               ei, ei + E, ew, hist, btot, stage, E, epb);
  k_bucket<<<dim3(nbk), B, 0, stream>>>(stage, btot, col, ninfo, n);
  k_agg1<<<dim3((n + 15) / 16), B, 0, stream>>>(ninfo, col,
                                                (const float2*)a_src1v,
                                                (const float2*)a_dst1v,
                                                scal, xs_bf, b1, h1, n);
  k_gemm_mfma1<<<dim3((n + 63) / 64), B, 0, stream>>>(h1, bfrag2, xs_bf, as2, ad2,
                                                      a_src2v, a_dst2v, n);
  k_agg2<<<dim3((n + 31) / 32), B, 0, stream>>>(ninfo, col, a_src2v, a_dst2v,
                                                scal, xs_bf, b2, (float*)d_out, n);
}